// Round 1
// baseline (115.988 us; speedup 1.0000x reference)
//
#include <hip/hip_runtime.h>
#include <hip/hip_bf16.h>

#define BATCH   8
#define NODES   8192
#define CH      128            // CH_IN == CH_OUT
#define NEXP    64
#define TN      16             // nodes per GEMM tile (M = 8*16 = 128 rows)
#define MAXP    (NODES + NEXP * TN)   // padded sorted-list capacity = 9216
#define NTILES  (MAXP / TN)           // 576 blocks

typedef __attribute__((ext_vector_type(8))) short bf16x8;  // 8 bf16 = 4 VGPRs
typedef __attribute__((ext_vector_type(4))) float f32x4;

__device__ __forceinline__ short f2bf(float f) {
    // round-to-nearest-even fp32 -> bf16
    union { float f; unsigned u; } v; v.f = f;
    unsigned r = (v.u + 0x7fffu + ((v.u >> 16) & 1u)) >> 16;
    return (short)r;
}

__device__ __forceinline__ bf16x8 cvt8(f32x4 lo, f32x4 hi) {
    bf16x8 r;
    r[0] = f2bf(lo[0]); r[1] = f2bf(lo[1]); r[2] = f2bf(lo[2]); r[3] = f2bf(lo[3]);
    r[4] = f2bf(hi[0]); r[5] = f2bf(hi[1]); r[6] = f2bf(hi[2]); r[7] = f2bf(hi[3]);
    return r;
}

// ---------------------------------------------------------------------------
// Kernel 1: single-block counting sort of node ids by expert, with each
// expert segment padded to a multiple of TN (pad slots = -1). LDS counters,
// so no workspace pre-zeroing is needed (d_ws arrives poisoned 0xAA).
// ---------------------------------------------------------------------------
__global__ __launch_bounds__(1024)
void sort_kernel(const int* __restrict__ sel, int* __restrict__ sorted)
{
    __shared__ int cnt[NEXP];
    __shared__ int cur[NEXP];
    const int t = threadIdx.x;

    if (t < NEXP) cnt[t] = 0;
    __syncthreads();

    int mye[NODES / 1024];
    #pragma unroll
    for (int i = 0; i < NODES / 1024; ++i) {
        mye[i] = sel[i * 1024 + t];
        atomicAdd(&cnt[mye[i]], 1);
    }
    __syncthreads();

    if (t == 0) {
        int off = 0;
        for (int e = 0; e < NEXP; ++e) {
            cur[e] = off;
            off += (cnt[e] + TN - 1) & ~(TN - 1);
        }
    }
    __syncthreads();

    for (int i = t; i < MAXP; i += 1024) sorted[i] = -1;
    __syncthreads();   // order fill before scatter (same block -> ordered)

    #pragma unroll
    for (int i = 0; i < NODES / 1024; ++i) {
        int pos = atomicAdd(&cur[mye[i]], 1);
        sorted[pos] = i * 1024 + t;
    }
}

// ---------------------------------------------------------------------------
// Kernel 2: grouped GEMM. Block = one tile of 16 nodes (single expert due to
// segment padding). M = 128 rows (row r = node_idx*8 + b), N = 128, K = 128.
// 4 waves; wave w owns rows [w*32, w*32+32) x all 128 cols
// = 2 row-tiles x 8 col-tiles of mfma_f32_16x16x32_bf16.
// A/B fragments loaded straight from global (L2-resident W), fp32->bf16 in
// register. Padded rows load node 0 (safe addr) and are simply not stored.
// ---------------------------------------------------------------------------
__global__ __launch_bounds__(256)
void gemm_kernel(const float* __restrict__ x, const int* __restrict__ sel,
                 const float* __restrict__ W, float* __restrict__ out,
                 const int* __restrict__ sorted)
{
    __shared__ int s_nodes[TN];
    __shared__ int s_expert;

    const int tid  = threadIdx.x;
    const int tile = blockIdx.x;

    if (tid < TN) s_nodes[tid] = sorted[tile * TN + tid];
    if (tid == 0) {
        int n0 = sorted[tile * TN];
        s_expert = (n0 >= 0) ? sel[n0] : -1;
    }
    __syncthreads();

    const int e = s_expert;
    if (e < 0) return;                       // fully-padded / unused tile

    const int wave = tid >> 6;               // 0..3
    const int lane = tid & 63;
    const int m16  = lane & 15;              // row (A) / col (B,D) within 16-tile
    const int quad = lane >> 4;              // 0..3 -> k-subblock / D-row group

    // x row pointers for this lane's A-fragment rows (2 row-tiles)
    const float* xrow[2];
    #pragma unroll
    for (int rt = 0; rt < 2; ++rt) {
        int r    = wave * 32 + rt * 16 + m16;        // block-local row
        int node = s_nodes[r >> 3];
        int b    = r & 7;
        int nd   = (node >= 0) ? node : 0;           // safe address for pads
        xrow[rt] = x + ((size_t)(b * NODES + nd)) * CH;
    }
    const float* wbase = W + (size_t)e * CH * CH;

    f32x4 acc[2][8];
    #pragma unroll
    for (int rt = 0; rt < 2; ++rt)
        #pragma unroll
        for (int ct = 0; ct < 8; ++ct)
            acc[rt][ct] = (f32x4){0.f, 0.f, 0.f, 0.f};

    #pragma unroll
    for (int kk = 0; kk < 4; ++kk) {
        const int k0 = kk * 32 + quad * 8;           // this lane's 8-k chunk

        bf16x8 afrag[2];
        #pragma unroll
        for (int rt = 0; rt < 2; ++rt) {
            const float* p = xrow[rt] + k0;
            f32x4 lo = *reinterpret_cast<const f32x4*>(p);
            f32x4 hi = *reinterpret_cast<const f32x4*>(p + 4);
            afrag[rt] = cvt8(lo, hi);
        }

        #pragma unroll
        for (int ct = 0; ct < 8; ++ct) {
            const float* p = wbase + (size_t)(ct * 16 + m16) * CH + k0;
            f32x4 lo = *reinterpret_cast<const f32x4*>(p);
            f32x4 hi = *reinterpret_cast<const f32x4*>(p + 4);
            bf16x8 bfrag = cvt8(lo, hi);             // B[k][n] = W[n][k]
            acc[0][ct] = __builtin_amdgcn_mfma_f32_16x16x32_bf16(
                             afrag[0], bfrag, acc[0][ct], 0, 0, 0);
            acc[1][ct] = __builtin_amdgcn_mfma_f32_16x16x32_bf16(
                             afrag[1], bfrag, acc[1][ct], 0, 0, 0);
        }
    }

    // D layout: col = lane&15, row = quad*4 + reg  (m89/m91-verified)
    #pragma unroll
    for (int rt = 0; rt < 2; ++rt) {
        #pragma unroll
        for (int reg = 0; reg < 4; ++reg) {
            int r    = wave * 32 + rt * 16 + quad * 4 + reg;
            int node = s_nodes[r >> 3];
            if (node < 0) continue;                  // padded row: drop
            int b = r & 7;
            float* orow = out + ((size_t)(b * NODES + node)) * CH;
            #pragma unroll
            for (int ct = 0; ct < 8; ++ct)
                orow[ct * 16 + m16] = acc[rt][ct][reg];
        }
    }
}

extern "C" void kernel_launch(void* const* d_in, const int* in_sizes, int n_in,
                              void* d_out, int out_size, void* d_ws, size_t ws_size,
                              hipStream_t stream)
{
    const float* x   = (const float*)d_in[0];
    const int*   sel = (const int*)  d_in[1];
    const float* W   = (const float*)d_in[2];
    float*       out = (float*)d_out;
    int*      sorted = (int*)d_ws;                   // 9216 ints = 36 KB

    sort_kernel<<<1, 1024, 0, stream>>>(sel, sorted);
    gemm_kernel<<<NTILES, 256, 0, stream>>>(x, sel, W, out, sorted);
}

// Round 2
// 115.513 us; speedup vs baseline: 1.0041x; 1.0041x over previous
//
#include <hip/hip_runtime.h>
#include <hip/hip_bf16.h>

#define BATCH   8
#define NODES   8192
#define CH      128            // CH_IN == CH_OUT
#define NEXP    64
#define TN      16             // nodes per GEMM tile (M = 8*16 = 128 rows)
#define MAXP    (NODES + NEXP * TN)   // padded sorted-list capacity = 9216
#define NTILES  (MAXP / TN)           // 576 blocks

typedef __attribute__((ext_vector_type(8))) short bf16x8;  // 8 bf16 = 4 VGPRs
typedef __attribute__((ext_vector_type(4))) float f32x4;

__device__ __forceinline__ short f2bf(float f) {
    // round-to-nearest-even fp32 -> bf16
    union { float f; unsigned u; } v; v.f = f;
    unsigned r = (v.u + 0x7fffu + ((v.u >> 16) & 1u)) >> 16;
    return (short)r;
}

__device__ __forceinline__ bf16x8 cvt8(f32x4 lo, f32x4 hi) {
    bf16x8 r;
    r[0] = f2bf(lo[0]); r[1] = f2bf(lo[1]); r[2] = f2bf(lo[2]); r[3] = f2bf(lo[3]);
    r[4] = f2bf(hi[0]); r[5] = f2bf(hi[1]); r[6] = f2bf(hi[2]); r[7] = f2bf(hi[3]);
    return r;
}

// ---------------------------------------------------------------------------
// Prep kernel: 64 blocks, block e does TWO independent jobs:
//  (a) convert W[e] (128x128 fp32) -> bf16 into Wbf[e] (d_ws, L2-resident)
//  (b) counting-sort segment for expert e: histogram all of sel (32 KB,
//      L2-hot after first block), derive own padded prefix offset, compact
//      matching node ids into sorted[off .. off+cnt), pad tail with -1.
// Block 63 additionally -1-fills the global tail so unused GEMM tiles see
// a negative sentinel (d_ws arrives poisoned, 0xAA.. is negative, but be
// explicit).
// ---------------------------------------------------------------------------
__global__ __launch_bounds__(256)
void prep_kernel(const int* __restrict__ sel, const float* __restrict__ W,
                 short* __restrict__ Wbf, int* __restrict__ sorted)
{
    const int e = blockIdx.x;
    const int t = threadIdx.x;

    // (a) W[e] fp32 -> bf16, 16384 elems, 8 per thread-iter
    {
        const float* ws = W   + (size_t)e * CH * CH;
        short*       wd = Wbf + (size_t)e * CH * CH;
        #pragma unroll
        for (int i = 0; i < 8; ++i) {
            int idx = (i * 256 + t) * 8;
            f32x4 lo = *reinterpret_cast<const f32x4*>(ws + idx);
            f32x4 hi = *reinterpret_cast<const f32x4*>(ws + idx + 4);
            *reinterpret_cast<bf16x8*>(wd + idx) = cvt8(lo, hi);
        }
    }

    // (b) sort segment for expert e
    __shared__ int cnt[NEXP];
    __shared__ int s_off, s_cnt, cursor;
    if (t < NEXP) cnt[t] = 0;
    if (t == 0) cursor = 0;
    __syncthreads();

    int myv[NODES / 256];
    #pragma unroll
    for (int i = 0; i < NODES / 256; ++i) {
        myv[i] = sel[i * 256 + t];
        atomicAdd(&cnt[myv[i]], 1);
    }
    __syncthreads();

    if (t == 0) {
        int off = 0, myoff = 0;
        for (int ee = 0; ee < NEXP; ++ee) {
            if (ee == e) myoff = off;
            off += (cnt[ee] + TN - 1) & ~(TN - 1);
        }
        s_off = myoff;
        s_cnt = cnt[e];
    }
    __syncthreads();

    const int off = s_off, myc = s_cnt;
    const int pad = (myc + TN - 1) & ~(TN - 1);

    for (int i = myc + t; i < pad; i += 256) sorted[off + i] = -1;

    if (e == NEXP - 1) {          // global tail (off+pad == total here)
        for (int i = off + pad + t; i < MAXP; i += 256) sorted[i] = -1;
    }

    #pragma unroll
    for (int i = 0; i < NODES / 256; ++i) {
        if (myv[i] == e) {
            int pos = atomicAdd(&cursor, 1);
            sorted[off + pos] = i * 256 + t;   // disjoint from -1 pad region
        }
    }
}

// ---------------------------------------------------------------------------
// Kernel 2: grouped GEMM. Block = one tile of 16 nodes (single expert due to
// segment padding). M = 128 rows (row r = node_idx*8 + b), N = 128, K = 128.
// 4 waves; wave w owns rows [w*32, w*32+32) x all 128 cols
// = 2 row-tiles x 8 col-tiles of mfma_f32_16x16x32_bf16.
// A converted fp32->bf16 in-register; B loaded directly as bf16 from Wbf
// (L2-resident, no conversion). Padded rows load node 0 and aren't stored.
// ---------------------------------------------------------------------------
__global__ __launch_bounds__(256)
void gemm_kernel(const float* __restrict__ x, const int* __restrict__ sel,
                 const short* __restrict__ Wbf, float* __restrict__ out,
                 const int* __restrict__ sorted)
{
    __shared__ int s_nodes[TN];
    __shared__ int s_expert;

    const int tid  = threadIdx.x;
    const int tile = blockIdx.x;

    if (tid < TN) s_nodes[tid] = sorted[tile * TN + tid];
    if (tid == 0) {
        int n0 = sorted[tile * TN];
        s_expert = (n0 >= 0) ? sel[n0] : -1;
    }
    __syncthreads();

    const int e = s_expert;
    if (e < 0) return;                       // unused tile

    const int wave = tid >> 6;               // 0..3
    const int lane = tid & 63;
    const int m16  = lane & 15;              // row (A) / col (B,D) within 16-tile
    const int quad = lane >> 4;              // 0..3 -> k-subblock / D-row group

    const float* xrow[2];
    #pragma unroll
    for (int rt = 0; rt < 2; ++rt) {
        int r    = wave * 32 + rt * 16 + m16;        // block-local row
        int node = s_nodes[r >> 3];
        int b    = r & 7;
        int nd   = (node >= 0) ? node : 0;           // safe address for pads
        xrow[rt] = x + ((size_t)(b * NODES + nd)) * CH;
    }
    const short* wbase = Wbf + (size_t)e * CH * CH;

    f32x4 acc[2][8];
    #pragma unroll
    for (int rt = 0; rt < 2; ++rt)
        #pragma unroll
        for (int ct = 0; ct < 8; ++ct)
            acc[rt][ct] = (f32x4){0.f, 0.f, 0.f, 0.f};

    #pragma unroll
    for (int kk = 0; kk < 4; ++kk) {
        const int k0 = kk * 32 + quad * 8;           // this lane's 8-k chunk

        bf16x8 afrag[2];
        #pragma unroll
        for (int rt = 0; rt < 2; ++rt) {
            const float* p = xrow[rt] + k0;
            f32x4 lo = *reinterpret_cast<const f32x4*>(p);
            f32x4 hi = *reinterpret_cast<const f32x4*>(p + 4);
            afrag[rt] = cvt8(lo, hi);
        }

        #pragma unroll
        for (int ct = 0; ct < 8; ++ct) {
            bf16x8 bfrag = *reinterpret_cast<const bf16x8*>(
                wbase + (size_t)(ct * 16 + m16) * CH + k0);   // B[k][n]=W[n][k]
            acc[0][ct] = __builtin_amdgcn_mfma_f32_16x16x32_bf16(
                             afrag[0], bfrag, acc[0][ct], 0, 0, 0);
            acc[1][ct] = __builtin_amdgcn_mfma_f32_16x16x32_bf16(
                             afrag[1], bfrag, acc[1][ct], 0, 0, 0);
        }
    }

    // D layout: col = lane&15, row = quad*4 + reg  (m89/m91-verified)
    #pragma unroll
    for (int rt = 0; rt < 2; ++rt) {
        #pragma unroll
        for (int reg = 0; reg < 4; ++reg) {
            int r    = wave * 32 + rt * 16 + quad * 4 + reg;
            int node = s_nodes[r >> 3];
            if (node < 0) continue;                  // padded row: drop
            int b = r & 7;
            float* orow = out + ((size_t)(b * NODES + node)) * CH;
            #pragma unroll
            for (int ct = 0; ct < 8; ++ct)
                orow[ct * 16 + m16] = acc[rt][ct][reg];
        }
    }
}

extern "C" void kernel_launch(void* const* d_in, const int* in_sizes, int n_in,
                              void* d_out, int out_size, void* d_ws, size_t ws_size,
                              hipStream_t stream)
{
    const float* x   = (const float*)d_in[0];
    const int*   sel = (const int*)  d_in[1];
    const float* W   = (const float*)d_in[2];
    float*       out = (float*)d_out;

    short* Wbf   = (short*)d_ws;                             // 2 MiB
    int*   sorted = (int*)((char*)d_ws + (size_t)NEXP * CH * CH * sizeof(short));

    prep_kernel<<<NEXP, 256, 0, stream>>>(sel, W, Wbf, sorted);
    gemm_kernel<<<NTILES, 256, 0, stream>>>(x, sel, Wbf, out, sorted);
}